// Round 11
// baseline (5408.284 us; speedup 1.0000x reference)
//
#include <hip/hip_runtime.h>
#include <hip/hip_bf16.h>

#define B_ 2
#define S_ 2048
#define HID_ 1536
#define H_ 12
#define HD_ 128
#define LAT_ 192
#define ROT_ 64
#define M_ (B_*S_)   // 4096

typedef __hip_bfloat16 bf16;

__global__ __launch_bounds__(256)
void fillf_k(float* __restrict__ out, float v, int n)
{
  int i = blockIdx.x*256 + threadIdx.x;
  if (i < n) out[i] = v;
}

// ---------------------------------------------------------------------------
// Plain tiled GEMM: C(M,N) = A(M,K) @ Bw(K,N), fp32 accumulate.
// A: fp32 (ABF=0) or bf16 (ABF=1). C: fp32 (CBF=0) or bf16 (CBF=1).
// Tile 64x64, BK=16, 256 threads, 4x4 microtile.
// ---------------------------------------------------------------------------
template<int ABF, int CBF>
__global__ __launch_bounds__(256)
void gemm2(const void* __restrict__ Av, const float* __restrict__ Bw,
           void* __restrict__ Cv, int Mn, int Nn, int Kn)
{
  __shared__ float As[16][64];                    // [k][m]
  __shared__ float Bs[16][64];                    // [k][n]

  const int tx = threadIdx.x, ty = threadIdx.y;
  const int tid = ty*16 + tx;
  const int n0 = blockIdx.x * 64, m0 = blockIdx.y * 64;

  float acc[4][4];
  #pragma unroll
  for (int i=0;i<4;i++)
    #pragma unroll
    for (int j=0;j<4;j++) acc[i][j] = 0.f;

  for (int k0 = 0; k0 < Kn; k0 += 16) {
    #pragma unroll
    for (int i = 0; i < 4; i++) {                 // A tile 64x16 -> As[c][r]
      int idx = tid*4 + i;
      int r = idx >> 4, c = idx & 15;
      if (ABF) As[c][r] = __bfloat162float(((const bf16*)Av)[(size_t)(m0+r)*Kn + (k0+c)]);
      else     As[c][r] = ((const float*)Av)[(size_t)(m0+r)*Kn + (k0+c)];
    }
    #pragma unroll
    for (int i = 0; i < 4; i++) {                 // B tile 16x64 -> Bs[c][n]
      int idx = tid*4 + i;
      int c = idx >> 6, n = idx & 63;
      Bs[c][n] = Bw[(size_t)(k0+c)*Nn + (n0+n)];
    }
    __syncthreads();
    #pragma unroll
    for (int kk = 0; kk < 16; kk++) {
      float4 a4 = *(const float4*)&As[kk][ty*4];
      float4 b4 = *(const float4*)&Bs[kk][tx*4];
      float av[4] = {a4.x, a4.y, a4.z, a4.w};
      float bv[4] = {b4.x, b4.y, b4.z, b4.w};
      #pragma unroll
      for (int i=0;i<4;i++)
        #pragma unroll
        for (int j=0;j<4;j++) acc[i][j] += av[i]*bv[j];
    }
    __syncthreads();
  }

  #pragma unroll
  for (int i=0;i<4;i++)
    #pragma unroll
    for (int j=0;j<4;j++) {
      size_t off = (size_t)(m0 + ty*4 + i)*Nn + (n0 + tx*4 + j);
      if (CBF) ((bf16*)Cv)[off] = __float2bfloat16(acc[i][j]);
      else     ((float*)Cv)[off] = acc[i][j];
    }
}

// ---------------------------------------------------------------------------
// Standalone rope, in-place on the flat (M, 768) k_r and q_r buffers.
// ---------------------------------------------------------------------------
__global__ __launch_bounds__(256)
void rope_k(float* __restrict__ kr, float* __restrict__ qr,
            const float* __restrict__ emb)
{
  int idx = blockIdx.x*256 + threadIdx.x;        // < M*H*32 = 1572864
  int i = idx & 31;
  int hm = idx >> 5;
  int h = hm % H_, m = hm / H_;
  int s = m % S_;
  float sn = emb[(size_t)s*ROT_ + i];
  float cs = emb[(size_t)s*ROT_ + 32 + i];

  float* r1 = kr + (size_t)m*(H_*ROT_) + h*ROT_;
  float x1 = r1[i], x2 = r1[32+i];
  r1[i]    = x1*cs - x2*sn;
  r1[32+i] = x1*sn + x2*cs;

  float* r2 = qr + (size_t)m*(H_*ROT_) + h*ROT_;
  x1 = r2[i]; x2 = r2[32+i];
  r2[i]    = x1*cs - x2*sn;
  r2[32+i] = x1*sn + x2*cs;
}

// ---------------------------------------------------------------------------
// Naive exact-softmax causal attention. One block per (b, h, q); 256 threads.
// ---------------------------------------------------------------------------
__global__ __launch_bounds__(256)
void attn_naive(const float* __restrict__ qc, const float* __restrict__ qr,
                const float* __restrict__ kc, const float* __restrict__ kr,
                const bf16* __restrict__ vfl, bf16* __restrict__ at)
{
  const int q  = blockIdx.x % S_;
  const int bh = blockIdx.x / S_;
  const int h  = bh % H_, b = bh / H_;
  const int tid = threadIdx.x;

  __shared__ float qs[128];
  __shared__ float sc[S_];
  __shared__ float red[256];

  const size_t mq = (size_t)b*S_ + q;
  if (tid < 64)       qs[tid] = qc[mq*(H_*ROT_) + h*ROT_ + tid];
  else if (tid < 128) qs[tid] = qr[mq*(H_*ROT_) + h*ROT_ + (tid-64)];
  __syncthreads();

  const int nk = q + 1;                       // causal: keys 0..q
  const float scale = 0.08838834764831845f;   // 1/sqrt(128)

  for (int k = tid; k < nk; k += 256) {
    const size_t mk = (size_t)b*S_ + k;
    const float* kcr = kc + mk*(H_*ROT_) + h*ROT_;
    const float* krr = kr + mk*(H_*ROT_) + h*ROT_;
    float s = 0.f;
    for (int d = 0; d < 64; d++) s += qs[d]      * kcr[d];
    for (int d = 0; d < 64; d++) s += qs[64 + d] * krr[d];
    sc[k] = s * scale;
  }
  __syncthreads();

  float mx = -1e30f;
  for (int k = tid; k < nk; k += 256) mx = fmaxf(mx, sc[k]);
  red[tid] = mx; __syncthreads();
  for (int w = 128; w >= 1; w >>= 1) {
    if (tid < w) red[tid] = fmaxf(red[tid], red[tid+w]);
    __syncthreads();
  }
  mx = red[0]; __syncthreads();

  float ls = 0.f;
  for (int k = tid; k < nk; k += 256) {
    float p = __expf(sc[k] - mx);
    sc[k] = p; ls += p;
  }
  red[tid] = ls; __syncthreads();
  for (int w = 128; w >= 1; w >>= 1) {
    if (tid < w) red[tid] += red[tid+w];
    __syncthreads();
  }
  const float linv = 1.f / red[0];

  if (tid < 128) {
    float o = 0.f;
    for (int k = 0; k < nk; k++)
      o += sc[k] * __bfloat162float(vfl[((size_t)b*S_ + k)*HID_ + h*HD_ + tid]);
    at[mq*HID_ + h*HD_ + tid] = __float2bfloat16(o * linv);
  }
}

extern "C" void kernel_launch(void* const* d_in, const int* in_sizes, int n_in,
                              void* d_out, int out_size, void* d_ws, size_t ws_size,
                              hipStream_t stream)
{
  float* out = (float*)d_out;      // <-- OUTPUT IS FP32 (reference returns float32)

  // Size guard (verified passing in r8; tripwire kept).
  static const int sz_dict[10] = {6291456,131072,294912,294912,147456,
                                  147456,294912,1179648,147456,2359296};
  int bad = -1;
  if (n_in < 10) bad = 15;
  else {
    for (int i = 0; i < 10; i++)
      if (in_sizes[i] != sz_dict[i]) { bad = i; break; }
  }
  if (bad >= 0) {
    float v = 1.0e6f * (float)(1 + bad);
    if (bad < 10) v += (float)(in_sizes[bad] % 1000000);
    fillf_k<<<(out_size + 255)/256, 256, 0, stream>>>(out, v, out_size);
    return;
  }

  const float* hidden = (const float*)d_in[0];
  const float* emb    = (const float*)d_in[1];
  const float* Wkvd   = (const float*)d_in[2];
  const float* Wqd    = (const float*)d_in[3];
  const float* Wku    = (const float*)d_in[4];
  const float* Wqu    = (const float*)d_in[5];
  const float* Wvu    = (const float*)d_in[6];
  const float* Wrk    = (const float*)d_in[7];
  const float* Wrq    = (const float*)d_in[8];
  const float* Wo     = (const float*)d_in[9];

  // ws: flat fp32 buffers, v/at bf16. Total ~82 MB (ran fine in r6).
  float* kvd = (float*)d_ws;                     // (M,192) fp32
  float* qd  = kvd + (size_t)M_*LAT_;            // (M,192) fp32
  float* kc  = qd  + (size_t)M_*LAT_;            // (M,768) fp32
  float* qc  = kc  + (size_t)M_*(H_*ROT_);       // (M,768) fp32
  float* krr = qc  + (size_t)M_*(H_*ROT_);       // (M,768) fp32
  float* qrr = krr + (size_t)M_*(H_*ROT_);       // (M,768) fp32
  bf16*  vfl = (bf16*)(qrr + (size_t)M_*(H_*ROT_)); // (M,1536) bf16
  bf16*  at  = vfl + (size_t)M_*HID_;            // (M,1536) bf16

  dim3 blk(16,16);
  gemm2<0,0><<<dim3(LAT_/64,      M_/64), blk, 0, stream>>>(hidden, Wkvd, kvd, M_, LAT_,     HID_);
  gemm2<0,0><<<dim3(LAT_/64,      M_/64), blk, 0, stream>>>(hidden, Wqd,  qd,  M_, LAT_,     HID_);
  gemm2<0,0><<<dim3((H_*ROT_)/64, M_/64), blk, 0, stream>>>(kvd,    Wku,  kc,  M_, H_*ROT_,  LAT_);
  gemm2<0,0><<<dim3((H_*ROT_)/64, M_/64), blk, 0, stream>>>(qd,     Wqu,  qc,  M_, H_*ROT_,  LAT_);
  gemm2<0,1><<<dim3(HID_/64,      M_/64), blk, 0, stream>>>(kvd,    Wvu,  vfl, M_, HID_,     LAT_);
  gemm2<0,0><<<dim3((HID_/2)/64,  M_/64), blk, 0, stream>>>(hidden, Wrk,  krr, M_, HID_/2,   HID_);
  gemm2<0,0><<<dim3((HID_/2)/64,  M_/64), blk, 0, stream>>>(qd,     Wrq,  qrr, M_, HID_/2,   LAT_);
  rope_k<<<(M_*H_*32)/256, 256, 0, stream>>>(krr, qrr, emb);
  attn_naive<<<B_*H_*S_, 256, 0, stream>>>(qc, qrr, kc, krr, vfl, at);
  // final GEMM stores FP32 to d_out
  gemm2<1,0><<<dim3(HID_/64, M_/64), blk, 0, stream>>>(at, Wo, out, M_, HID_, HID_);
}

// Round 12
// 2114.001 us; speedup vs baseline: 2.5583x; 2.5583x over previous
//
#include <hip/hip_runtime.h>
#include <hip/hip_bf16.h>

#define B_ 2
#define S_ 2048
#define HID_ 1536
#define H_ 12
#define HD_ 128
#define LAT_ 192
#define ROT_ 64
#define M_ (B_*S_)   // 4096

typedef __hip_bfloat16 bf16;

__global__ __launch_bounds__(256)
void fillf_k(float* __restrict__ out, float v, int n)
{
  int i = blockIdx.x*256 + threadIdx.x;
  if (i < n) out[i] = v;
}

// ---------------------------------------------------------------------------
// Plain tiled GEMM: C(M,N) = A(M,K) @ Bw(K,N), fp32 accumulate.
// A: fp32 (ABF=0) or bf16 (ABF=1). C: fp32 (CBF=0) or bf16 (CBF=1).
// Tile 64x64, BK=16, 256 threads, 4x4 microtile.
// ---------------------------------------------------------------------------
template<int ABF, int CBF>
__global__ __launch_bounds__(256)
void gemm2(const void* __restrict__ Av, const float* __restrict__ Bw,
           void* __restrict__ Cv, int Mn, int Nn, int Kn)
{
  __shared__ float As[16][64];                    // [k][m]
  __shared__ float Bs[16][64];                    // [k][n]

  const int tx = threadIdx.x, ty = threadIdx.y;
  const int tid = ty*16 + tx;
  const int n0 = blockIdx.x * 64, m0 = blockIdx.y * 64;

  float acc[4][4];
  #pragma unroll
  for (int i=0;i<4;i++)
    #pragma unroll
    for (int j=0;j<4;j++) acc[i][j] = 0.f;

  for (int k0 = 0; k0 < Kn; k0 += 16) {
    #pragma unroll
    for (int i = 0; i < 4; i++) {                 // A tile 64x16 -> As[c][r]
      int idx = tid*4 + i;
      int r = idx >> 4, c = idx & 15;
      if (ABF) As[c][r] = __bfloat162float(((const bf16*)Av)[(size_t)(m0+r)*Kn + (k0+c)]);
      else     As[c][r] = ((const float*)Av)[(size_t)(m0+r)*Kn + (k0+c)];
    }
    #pragma unroll
    for (int i = 0; i < 4; i++) {                 // B tile 16x64 -> Bs[c][n]
      int idx = tid*4 + i;
      int c = idx >> 6, n = idx & 63;
      Bs[c][n] = Bw[(size_t)(k0+c)*Nn + (n0+n)];
    }
    __syncthreads();
    #pragma unroll
    for (int kk = 0; kk < 16; kk++) {
      float4 a4 = *(const float4*)&As[kk][ty*4];
      float4 b4 = *(const float4*)&Bs[kk][tx*4];
      float av[4] = {a4.x, a4.y, a4.z, a4.w};
      float bv[4] = {b4.x, b4.y, b4.z, b4.w};
      #pragma unroll
      for (int i=0;i<4;i++)
        #pragma unroll
        for (int j=0;j<4;j++) acc[i][j] += av[i]*bv[j];
    }
    __syncthreads();
  }

  #pragma unroll
  for (int i=0;i<4;i++)
    #pragma unroll
    for (int j=0;j<4;j++) {
      size_t off = (size_t)(m0 + ty*4 + i)*Nn + (n0 + tx*4 + j);
      if (CBF) ((bf16*)Cv)[off] = __float2bfloat16(acc[i][j]);
      else     ((float*)Cv)[off] = acc[i][j];
    }
}

// ---------------------------------------------------------------------------
// Standalone rope, in-place on the flat (M, 768) k_r and q_r buffers.
// ---------------------------------------------------------------------------
__global__ __launch_bounds__(256)
void rope_k(float* __restrict__ kr, float* __restrict__ qr,
            const float* __restrict__ emb)
{
  int idx = blockIdx.x*256 + threadIdx.x;        // < M*H*32 = 1572864
  int i = idx & 31;
  int hm = idx >> 5;
  int h = hm % H_, m = hm / H_;
  int s = m % S_;
  float sn = emb[(size_t)s*ROT_ + i];
  float cs = emb[(size_t)s*ROT_ + 32 + i];

  float* r1 = kr + (size_t)m*(H_*ROT_) + h*ROT_;
  float x1 = r1[i], x2 = r1[32+i];
  r1[i]    = x1*cs - x2*sn;
  r1[32+i] = x1*sn + x2*cs;

  float* r2 = qr + (size_t)m*(H_*ROT_) + h*ROT_;
  x1 = r2[i]; x2 = r2[32+i];
  r2[i]    = x1*cs - x2*sn;
  r2[32+i] = x1*sn + x2*cs;
}

// ---------------------------------------------------------------------------
// Flash attention, causal, 16-query tiles. Reads FLAT fp32 q/k buffers
// (split qc/qr halves) and flat bf16 v. One block = 16 queries; 256 threads
// as (tq,tc): QK: thread computes dot(q_tq, k_tc); PV: thread owns dims
// tc*8..tc*8+8. Output bf16 flat (b,s,h*d) for the final GEMM.
// ---------------------------------------------------------------------------
__global__ __launch_bounds__(256)
void attn_k(const float* __restrict__ qc, const float* __restrict__ qr,
            const float* __restrict__ kc, const float* __restrict__ kr,
            const bf16* __restrict__ vfl, bf16* __restrict__ at)
{
  const int qt = blockIdx.x % (S_/16);
  const int bh = blockIdx.x / (S_/16);
  const int h  = bh % H_, b = bh / H_;
  const int tid = threadIdx.x;
  const int tq = tid >> 4;
  const int tc = tid & 15;

  __shared__ float Qs[16][132];
  __shared__ float Ks[16][132];
  __shared__ float Vs[16][132];
  __shared__ float Ps[16][16];
  __shared__ float Ml[16], Ll[16];

  const int q0 = qt * 16;
  // load 16 q rows: dims 0..63 from qc, 64..127 from qr
  for (int p = tid; p < 16*HD_; p += 256) {
    int r = p >> 7, d = p & 127;
    const size_t mq = (size_t)b*S_ + (q0 + r);
    Qs[r][d] = (d < 64) ? qc[mq*(H_*ROT_) + h*ROT_ + d]
                        : qr[mq*(H_*ROT_) + h*ROT_ + (d - 64)];
  }
  if (tid < 16) { Ml[tid] = -1e30f; Ll[tid] = 0.f; }
  float o[8];
  #pragma unroll
  for (int j=0;j<8;j++) o[j] = 0.f;
  __syncthreads();

  const float scale = 0.08838834764831845f;   // 1/sqrt(128)
  const int qpos = q0 + tq;
  const int nkb = qt + 1;                     // causal: key blocks 0..qt

  for (int kb = 0; kb < nkb; kb++) {
    const int k0 = kb * 16;
    for (int p = tid; p < 16*HD_; p += 256) {
      int r = p >> 7, d = p & 127;
      const size_t mk = (size_t)b*S_ + (k0 + r);
      Ks[r][d] = (d < 64) ? kc[mk*(H_*ROT_) + h*ROT_ + d]
                          : kr[mk*(H_*ROT_) + h*ROT_ + (d - 64)];
      Vs[r][d] = __bfloat162float(vfl[mk*HID_ + h*HD_ + d]);
    }
    __syncthreads();

    // scores: dot(q_tq, k_tc)
    float s = 0.f;
    const float4* q4 = (const float4*)&Qs[tq][0];
    const float4* k4 = (const float4*)&Ks[tc][0];
    #pragma unroll
    for (int i = 0; i < 32; i++) {
      float4 a = q4[i], c = k4[i];
      s += a.x*c.x + a.y*c.y + a.z*c.z + a.w*c.w;
    }
    s *= scale;
    const int kpos = k0 + tc;
    if (kpos > qpos) s = -1e30f;

    // row max over the 16 lanes of this query (same wave, lockstep)
    float mt = s;
    #pragma unroll
    for (int off = 8; off >= 1; off >>= 1)
      mt = fmaxf(mt, __shfl_xor(mt, off, 16));
    float mprev = Ml[tq];
    float mnew = fmaxf(mprev, mt);
    float p_ = __expf(s - mnew);
    if (kpos > qpos) p_ = 0.f;
    float lt = p_;
    #pragma unroll
    for (int off = 8; off >= 1; off >>= 1)
      lt += __shfl_xor(lt, off, 16);
    float alpha = __expf(mprev - mnew);
    Ps[tq][tc] = p_;
    if (tc == 0) { Ml[tq] = mnew; Ll[tq] = Ll[tq]*alpha + lt; }
    #pragma unroll
    for (int j=0;j<8;j++) o[j] *= alpha;
    __syncthreads();

    // PV accumulate: dims tc*8..tc*8+8
    #pragma unroll
    for (int kk = 0; kk < 16; kk++) {
      float pv = Ps[tq][kk];
      const float4* v4 = (const float4*)&Vs[kk][tc*8];
      float4 vA = v4[0], vB = v4[1];
      o[0] += pv*vA.x; o[1] += pv*vA.y; o[2] += pv*vA.z; o[3] += pv*vA.w;
      o[4] += pv*vB.x; o[5] += pv*vB.y; o[6] += pv*vB.z; o[7] += pv*vB.w;
    }
    __syncthreads();
  }

  const float linv = 1.f / Ll[tq];
  const size_t mq = (size_t)b*S_ + (q0 + tq);
  bf16* dst = at + mq*HID_ + h*HD_ + tc*8;
  #pragma unroll
  for (int j=0;j<8;j++) dst[j] = __float2bfloat16(o[j]*linv);
}

extern "C" void kernel_launch(void* const* d_in, const int* in_sizes, int n_in,
                              void* d_out, int out_size, void* d_ws, size_t ws_size,
                              hipStream_t stream)
{
  float* out = (float*)d_out;      // fp32 output (verified r11)

  // Size guard tripwire.
  static const int sz_dict[10] = {6291456,131072,294912,294912,147456,
                                  147456,294912,1179648,147456,2359296};
  int bad = -1;
  if (n_in < 10) bad = 15;
  else {
    for (int i = 0; i < 10; i++)
      if (in_sizes[i] != sz_dict[i]) { bad = i; break; }
  }
  if (bad >= 0) {
    float v = 1.0e6f * (float)(1 + bad);
    if (bad < 10) v += (float)(in_sizes[bad] % 1000000);
    fillf_k<<<(out_size + 255)/256, 256, 0, stream>>>(out, v, out_size);
    return;
  }

  const float* hidden = (const float*)d_in[0];
  const float* emb    = (const float*)d_in[1];
  const float* Wkvd   = (const float*)d_in[2];
  const float* Wqd    = (const float*)d_in[3];
  const float* Wku    = (const float*)d_in[4];
  const float* Wqu    = (const float*)d_in[5];
  const float* Wvu    = (const float*)d_in[6];
  const float* Wrk    = (const float*)d_in[7];
  const float* Wrq    = (const float*)d_in[8];
  const float* Wo     = (const float*)d_in[9];

  // ws: flat fp32 buffers, v/at bf16. Total ~82 MB (r6/r11-proven).
  float* kvd = (float*)d_ws;                     // (M,192) fp32
  float* qd  = kvd + (size_t)M_*LAT_;            // (M,192) fp32
  float* kc  = qd  + (size_t)M_*LAT_;            // (M,768) fp32
  float* qc  = kc  + (size_t)M_*(H_*ROT_);       // (M,768) fp32
  float* krr = qc  + (size_t)M_*(H_*ROT_);       // (M,768) fp32
  float* qrr = krr + (size_t)M_*(H_*ROT_);       // (M,768) fp32
  bf16*  vfl = (bf16*)(qrr + (size_t)M_*(H_*ROT_)); // (M,1536) bf16
  bf16*  at  = vfl + (size_t)M_*HID_;            // (M,1536) bf16

  dim3 blk(16,16);
  gemm2<0,0><<<dim3(LAT_/64,      M_/64), blk, 0, stream>>>(hidden, Wkvd, kvd, M_, LAT_,     HID_);
  gemm2<0,0><<<dim3(LAT_/64,      M_/64), blk, 0, stream>>>(hidden, Wqd,  qd,  M_, LAT_,     HID_);
  gemm2<0,0><<<dim3((H_*ROT_)/64, M_/64), blk, 0, stream>>>(kvd,    Wku,  kc,  M_, H_*ROT_,  LAT_);
  gemm2<0,0><<<dim3((H_*ROT_)/64, M_/64), blk, 0, stream>>>(qd,     Wqu,  qc,  M_, H_*ROT_,  LAT_);
  gemm2<0,1><<<dim3(HID_/64,      M_/64), blk, 0, stream>>>(kvd,    Wvu,  vfl, M_, HID_,     LAT_);
  gemm2<0,0><<<dim3((HID_/2)/64,  M_/64), blk, 0, stream>>>(hidden, Wrk,  krr, M_, HID_/2,   HID_);
  gemm2<0,0><<<dim3((HID_/2)/64,  M_/64), blk, 0, stream>>>(qd,     Wrq,  qrr, M_, HID_/2,   LAT_);
  rope_k<<<(M_*H_*32)/256, 256, 0, stream>>>(krr, qrr, emb);
  // flash attention (16-query tiles)
  attn_k<<<B_*H_*(S_/16), 256, 0, stream>>>(qc, qrr, kc, krr, vfl, at);
  gemm2<1,0><<<dim3(HID_/64, M_/64), blk, 0, stream>>>(at, Wo, out, M_, HID_, HID_);
}

// Round 13
// 1222.256 us; speedup vs baseline: 4.4248x; 1.7296x over previous
//
#include <hip/hip_runtime.h>
#include <hip/hip_bf16.h>

#define B_ 2
#define S_ 2048
#define HID_ 1536
#define H_ 12
#define HD_ 128
#define LAT_ 192
#define ROT_ 64
#define M_ (B_*S_)   // 4096

typedef __hip_bfloat16 bf16;

using short8  = __attribute__((ext_vector_type(8))) short;
using short4v = __attribute__((ext_vector_type(4))) short;
using float4v = __attribute__((ext_vector_type(4))) float;

__device__ __forceinline__ unsigned short f2bf(float f) {
  __hip_bfloat16 h = __float2bfloat16(f);
  unsigned short u; __builtin_memcpy(&u, &h, 2); return u;
}

__global__ __launch_bounds__(256)
void fillf_k(float* __restrict__ out, float v, int n)
{
  int i = blockIdx.x*256 + threadIdx.x;
  if (i < n) out[i] = v;
}

// ---------------------------------------------------------------------------
// Plain tiled GEMM: C(M,N) = A(M,K) @ Bw(K,N), fp32 accumulate.
// ---------------------------------------------------------------------------
template<int ABF, int CBF>
__global__ __launch_bounds__(256)
void gemm2(const void* __restrict__ Av, const float* __restrict__ Bw,
           void* __restrict__ Cv, int Mn, int Nn, int Kn)
{
  __shared__ float As[16][64];
  __shared__ float Bs[16][64];

  const int tx = threadIdx.x, ty = threadIdx.y;
  const int tid = ty*16 + tx;
  const int n0 = blockIdx.x * 64, m0 = blockIdx.y * 64;

  float acc[4][4];
  #pragma unroll
  for (int i=0;i<4;i++)
    #pragma unroll
    for (int j=0;j<4;j++) acc[i][j] = 0.f;

  for (int k0 = 0; k0 < Kn; k0 += 16) {
    #pragma unroll
    for (int i = 0; i < 4; i++) {
      int idx = tid*4 + i;
      int r = idx >> 4, c = idx & 15;
      if (ABF) As[c][r] = __bfloat162float(((const bf16*)Av)[(size_t)(m0+r)*Kn + (k0+c)]);
      else     As[c][r] = ((const float*)Av)[(size_t)(m0+r)*Kn + (k0+c)];
    }
    #pragma unroll
    for (int i = 0; i < 4; i++) {
      int idx = tid*4 + i;
      int c = idx >> 6, n = idx & 63;
      Bs[c][n] = Bw[(size_t)(k0+c)*Nn + (n0+n)];
    }
    __syncthreads();
    #pragma unroll
    for (int kk = 0; kk < 16; kk++) {
      float4 a4 = *(const float4*)&As[kk][ty*4];
      float4 b4 = *(const float4*)&Bs[kk][tx*4];
      float av[4] = {a4.x, a4.y, a4.z, a4.w};
      float bv[4] = {b4.x, b4.y, b4.z, b4.w};
      #pragma unroll
      for (int i=0;i<4;i++)
        #pragma unroll
        for (int j=0;j<4;j++) acc[i][j] += av[i]*bv[j];
    }
    __syncthreads();
  }

  #pragma unroll
  for (int i=0;i<4;i++)
    #pragma unroll
    for (int j=0;j<4;j++) {
      size_t off = (size_t)(m0 + ty*4 + i)*Nn + (n0 + tx*4 + j);
      if (CBF) ((bf16*)Cv)[off] = __float2bfloat16(acc[i][j]);
      else     ((float*)Cv)[off] = acc[i][j];
    }
}

// ---------------------------------------------------------------------------
// Standalone rope, in-place on the flat (M, 768) k_r and q_r buffers.
// ---------------------------------------------------------------------------
__global__ __launch_bounds__(256)
void rope_k(float* __restrict__ kr, float* __restrict__ qr,
            const float* __restrict__ emb)
{
  int idx = blockIdx.x*256 + threadIdx.x;
  int i = idx & 31;
  int hm = idx >> 5;
  int h = hm % H_, m = hm / H_;
  int s = m % S_;
  float sn = emb[(size_t)s*ROT_ + i];
  float cs = emb[(size_t)s*ROT_ + 32 + i];

  float* r1 = kr + (size_t)m*(H_*ROT_) + h*ROT_;
  float x1 = r1[i], x2 = r1[32+i];
  r1[i]    = x1*cs - x2*sn;
  r1[32+i] = x1*sn + x2*cs;

  float* r2 = qr + (size_t)m*(H_*ROT_) + h*ROT_;
  x1 = r2[i]; x2 = r2[32+i];
  r2[i]    = x1*cs - x2*sn;
  r2[32+i] = x1*sn + x2*cs;
}

// ---------------------------------------------------------------------------
// MFMA flash attention, causal. Block = 4 waves = 64 queries; 32-key blocks.
// mfma_f32_16x16x32_bf16 layouts (verified m89/m120):
//   C/D: col=lane&15, row=quad*4+reg ; A: [m=lane&15][k=quad*8+j] ;
//   B:   [k=quad*8+j][n=lane&15].
// K staged row-major bf16 (stride 136 = 272B, 16B aligned);
// V staged TRANSPOSED Vt[dim][key] (stride 44 = 88B, 8B aligned);
// P round-trips C->A layout via per-wave LDS scratch.
// ---------------------------------------------------------------------------
#define KSTR 136
#define VSTR 44
#define PSTR 44

__global__ __launch_bounds__(256)
void attn_mfma(const float* __restrict__ qc, const float* __restrict__ qr,
               const float* __restrict__ kc, const float* __restrict__ kr,
               const bf16* __restrict__ vfl, bf16* __restrict__ at)
{
  const int qt = blockIdx.x % (S_/64);
  const int bh = blockIdx.x / (S_/64);
  const int h  = bh % H_, b = bh / H_;
  const int tid  = threadIdx.x;
  const int w    = tid >> 6;
  const int lane = tid & 63;
  const int col  = lane & 15;
  const int quad = lane >> 4;

  __shared__ unsigned short Ks[32*KSTR];        // 8704 B
  __shared__ unsigned short Vt[128*VSTR];       // 11264 B
  __shared__ unsigned short Ps[4][16*PSTR];     // 5632 B

  const int q0  = qt * 64;
  const int q0w = q0 + w*16;

  // Q fragments for 4 K-steps (dims 32kk..32kk+31), kept in registers.
  short8 qf[4];
  {
    const size_t mrow = (size_t)b*S_ + q0w + col;
    const float* qh0 = qc + mrow*(H_*ROT_) + h*ROT_;
    const float* qh1 = qr + mrow*(H_*ROT_) + h*ROT_;
    #pragma unroll
    for (int kk = 0; kk < 4; kk++) {
      const float* src = (kk < 2 ? qh0 + kk*32 : qh1 + (kk-2)*32) + quad*8;
      short8 v;
      #pragma unroll
      for (int j = 0; j < 8; j++) v[j] = (short)f2bf(src[j]);
      qf[kk] = v;
    }
  }

  float4v O[8];
  #pragma unroll
  for (int t=0;t<8;t++) O[t] = (float4v){0.f,0.f,0.f,0.f};
  float mrow[4], lrow[4];
  #pragma unroll
  for (int r=0;r<4;r++){ mrow[r] = -1e30f; lrow[r] = 0.f; }

  const float scale = 0.08838834764831845f;   // 1/sqrt(128)
  const int nkb = 2*(qt+1);                   // 32-key blocks

  for (int kb = 0; kb < nkb; kb++) {
    const int k0 = kb * 32;

    // stage K: 32 keys x 128 dims, packed bf16 pairs (8 dword writes/thread)
    for (int p = tid; p < 32*64; p += 256) {
      int key = p >> 6, j = p & 63;
      size_t mk = (size_t)b*S_ + k0 + key;
      const float* src = (j < 32) ? (kc + mk*(H_*ROT_) + h*ROT_ + 2*j)
                                  : (kr + mk*(H_*ROT_) + h*ROT_ + 2*j - 64);
      unsigned int packed = (unsigned int)f2bf(src[0]) |
                            ((unsigned int)f2bf(src[1]) << 16);
      *(unsigned int*)&Ks[key*KSTR + 2*j] = packed;
    }
    // stage V transposed: Vt[dim][key], packed key pairs
    for (int p = tid; p < 128*16; p += 256) {
      int d = p >> 4, kp = (p & 15)*2;
      const unsigned short* vr = (const unsigned short*)vfl;
      size_t base = ((size_t)b*S_ + k0 + kp)*HID_ + h*HD_ + d;
      unsigned int packed = (unsigned int)vr[base] |
                            ((unsigned int)vr[base + HID_] << 16);
      *(unsigned int*)&Vt[d*VSTR + kp] = packed;
    }
    __syncthreads();

    if (k0 <= q0w + 15) {                      // wave-uniform skip
      // ---- S = Q K^T : two 16x16 tiles (keys k0+col, k0+16+col) ----
      float4v Sf0 = (float4v){0,0,0,0}, Sf1 = (float4v){0,0,0,0};
      #pragma unroll
      for (int kk = 0; kk < 4; kk++) {
        short8 b0 = *(const short8*)&Ks[ col      *KSTR + 32*kk + quad*8];
        short8 b1 = *(const short8*)&Ks[(col+16)  *KSTR + 32*kk + quad*8];
        Sf0 = __builtin_amdgcn_mfma_f32_16x16x32_bf16(qf[kk], b0, Sf0, 0,0,0);
        Sf1 = __builtin_amdgcn_mfma_f32_16x16x32_bf16(qf[kk], b1, Sf1, 0,0,0);
      }

      // ---- online softmax (4 rows/lane: row = quad*4 + r) ----
      float al[4];
      #pragma unroll
      for (int r = 0; r < 4; r++) {
        const int qpos = q0w + quad*4 + r;
        float s0 = Sf0[r] * scale; if (k0 + col      > qpos) s0 = -1e30f;
        float s1 = Sf1[r] * scale; if (k0 + 16 + col > qpos) s1 = -1e30f;
        float mt = fmaxf(s0, s1);
        #pragma unroll
        for (int off = 8; off >= 1; off >>= 1)
          mt = fmaxf(mt, __shfl_xor(mt, off));
        float mnew = fmaxf(mrow[r], mt);
        float p0 = __expf(s0 - mnew);
        float p1 = __expf(s1 - mnew);
        float lt = p0 + p1;
        #pragma unroll
        for (int off = 8; off >= 1; off >>= 1)
          lt += __shfl_xor(lt, off);
        al[r] = __expf(mrow[r] - mnew);
        lrow[r] = lrow[r]*al[r] + lt;
        mrow[r] = mnew;
        const int prow = quad*4 + r;
        Ps[w][prow*PSTR + col]      = f2bf(p0);
        Ps[w][prow*PSTR + col + 16] = f2bf(p1);
      }
      // rescale O
      #pragma unroll
      for (int t = 0; t < 8; t++)
        #pragma unroll
        for (int r = 0; r < 4; r++) O[t][r] *= al[r];

      // ---- PV: P(16x32) @ V(32x128) -> 8 N-tiles ----
      short4v pa = *(const short4v*)&Ps[w][col*PSTR + quad*8];
      short4v pb = *(const short4v*)&Ps[w][col*PSTR + quad*8 + 4];
      short8 pf;
      #pragma unroll
      for (int j=0;j<4;j++){ pf[j] = pa[j]; pf[j+4] = pb[j]; }
      #pragma unroll
      for (int t = 0; t < 8; t++) {
        const unsigned short* vp = &Vt[(16*t + col)*VSTR + quad*8];
        short4v va = *(const short4v*)vp;
        short4v vb = *(const short4v*)(vp + 4);
        short8 vf;
        #pragma unroll
        for (int j=0;j<4;j++){ vf[j] = va[j]; vf[j+4] = vb[j]; }
        O[t] = __builtin_amdgcn_mfma_f32_16x16x32_bf16(pf, vf, O[t], 0,0,0);
      }
    }
    __syncthreads();
  }

  // epilogue: divide by l, store bf16 to flat at[(b,s,h*128)]
  #pragma unroll
  for (int r = 0; r < 4; r++) {
    const float linv = 1.f / lrow[r];
    const size_t mq = (size_t)b*S_ + q0w + quad*4 + r;
    bf16* dst = at + mq*HID_ + h*HD_ + col;
    #pragma unroll
    for (int t = 0; t < 8; t++)
      dst[16*t] = __float2bfloat16(O[t][r] * linv);
  }
}

extern "C" void kernel_launch(void* const* d_in, const int* in_sizes, int n_in,
                              void* d_out, int out_size, void* d_ws, size_t ws_size,
                              hipStream_t stream)
{
  float* out = (float*)d_out;      // fp32 output (verified r11)

  // Size guard tripwire.
  static const int sz_dict[10] = {6291456,131072,294912,294912,147456,
                                  147456,294912,1179648,147456,2359296};
  int bad = -1;
  if (n_in < 10) bad = 15;
  else {
    for (int i = 0; i < 10; i++)
      if (in_sizes[i] != sz_dict[i]) { bad = i; break; }
  }
  if (bad >= 0) {
    float v = 1.0e6f * (float)(1 + bad);
    if (bad < 10) v += (float)(in_sizes[bad] % 1000000);
    fillf_k<<<(out_size + 255)/256, 256, 0, stream>>>(out, v, out_size);
    return;
  }

  const float* hidden = (const float*)d_in[0];
  const float* emb    = (const float*)d_in[1];
  const float* Wkvd   = (const float*)d_in[2];
  const float* Wqd    = (const float*)d_in[3];
  const float* Wku    = (const float*)d_in[4];
  const float* Wqu    = (const float*)d_in[5];
  const float* Wvu    = (const float*)d_in[6];
  const float* Wrk    = (const float*)d_in[7];
  const float* Wrq    = (const float*)d_in[8];
  const float* Wo     = (const float*)d_in[9];

  // ws: flat fp32 buffers, v/at bf16. Total ~82 MB (r6/r11-proven).
  float* kvd = (float*)d_ws;                     // (M,192) fp32
  float* qd  = kvd + (size_t)M_*LAT_;            // (M,192) fp32
  float* kc  = qd  + (size_t)M_*LAT_;            // (M,768) fp32
  float* qc  = kc  + (size_t)M_*(H_*ROT_);       // (M,768) fp32
  float* krr = qc  + (size_t)M_*(H_*ROT_);       // (M,768) fp32
  float* qrr = krr + (size_t)M_*(H_*ROT_);       // (M,768) fp32
  bf16*  vfl = (bf16*)(qrr + (size_t)M_*(H_*ROT_)); // (M,1536) bf16
  bf16*  at  = vfl + (size_t)M_*HID_;            // (M,1536) bf16

  dim3 blk(16,16);
  gemm2<0,0><<<dim3(LAT_/64,      M_/64), blk, 0, stream>>>(hidden, Wkvd, kvd, M_, LAT_,     HID_);
  gemm2<0,0><<<dim3(LAT_/64,      M_/64), blk, 0, stream>>>(hidden, Wqd,  qd,  M_, LAT_,     HID_);
  gemm2<0,0><<<dim3((H_*ROT_)/64, M_/64), blk, 0, stream>>>(kvd,    Wku,  kc,  M_, H_*ROT_,  LAT_);
  gemm2<0,0><<<dim3((H_*ROT_)/64, M_/64), blk, 0, stream>>>(qd,     Wqu,  qc,  M_, H_*ROT_,  LAT_);
  gemm2<0,1><<<dim3(HID_/64,      M_/64), blk, 0, stream>>>(kvd,    Wvu,  vfl, M_, HID_,     LAT_);
  gemm2<0,0><<<dim3((HID_/2)/64,  M_/64), blk, 0, stream>>>(hidden, Wrk,  krr, M_, HID_/2,   HID_);
  gemm2<0,0><<<dim3((HID_/2)/64,  M_/64), blk, 0, stream>>>(qd,     Wrq,  qrr, M_, HID_/2,   LAT_);
  rope_k<<<(M_*H_*32)/256, 256, 0, stream>>>(krr, qrr, emb);
  // MFMA flash attention (64-query blocks, 32-key tiles)
  attn_mfma<<<B_*H_*(S_/64), 256, 0, stream>>>(qc, qrr, kc, krr, vfl, at);
  gemm2<1,0><<<dim3(HID_/64, M_/64), blk, 0, stream>>>(at, Wo, out, M_, HID_, HID_);
}